// Round 2
// baseline (355.081 us; speedup 1.0000x reference)
//
#include <hip/hip_runtime.h>
#include <math.h>

#define GAMMA_ 0.99f
#define GL_ (0.99f * 0.95f)
#define L_ 32            // chunk length (mask fits in u32)
#define PF 4             // software-pipeline depth (register prefetch slots)

typedef float    f2 __attribute__((ext_vector_type(2)));
typedef int      i2 __attribute__((ext_vector_type(2)));
typedef unsigned u2 __attribute__((ext_vector_type(2)));

// ---------------------------------------------------------------------------
// Pass 1: per (chunk, column-pair) reverse scan with zero carry, 2 columns
// per thread. HAND SOFTWARE-PIPELINED: PF=4 register slots for (r,v,d),
// fully unrolled so slot indices are static (registers, not scratch). Each
// slot's refill is issued ~3 computes (~150 cyc) before its reuse, keeping
// ~9-12 loads (~5 KB) in flight per wave; x16 waves/CU = ~80 KB/CU
// outstanding -> BW-bound, not latency-bound. (Round-0/1 evidence: compiler
// at VGPR_Count=32 serialized the loads -> 1.4 TB/s.)
// Also zeroes the double accumulators (replaces the hipMemsetAsync launch).
// ---------------------------------------------------------------------------
__global__ __launch_bounds__(256)
void gae_pass1(const f2* __restrict__ rw, const f2* __restrict__ vv,
               const i2* __restrict__ dn,
               f2* __restrict__ A, f2* __restrict__ B,
               f2* __restrict__ Sa, f2* __restrict__ Sa2,
               f2* __restrict__ SaP, f2* __restrict__ SP,
               f2* __restrict__ SP2, u2* __restrict__ mask,
               double* __restrict__ sums,
               int T, int N2)
{
    if (blockIdx.x == 0 && blockIdx.y == 0 && threadIdx.x == 0) {
        sums[0] = 0.0; sums[1] = 0.0;   // pass2 atomics start from zero
    }
    int q = blockIdx.x * blockDim.x + threadIdx.x;   // column-pair index
    int chunk = blockIdx.y;
    if (q >= N2) return;
    int s = chunk * L_;
    int e = s + L_; if (e > T) e = T;
    int len = e - s;

    float a[2]  = {0.f,0.f}, P[2]   = {1.f,1.f};
    float sa[2] = {0.f,0.f}, sa2[2] = {0.f,0.f};
    float saP[2]= {0.f,0.f}, sP[2]  = {0.f,0.f}, sP2[2] = {0.f,0.f};
    unsigned mm[2] = {0u,0u};

    f2 vn = vv[(size_t)e * N2 + q];
    float vnext[2] = {vn.x, vn.y};

    if (len == L_) {
        // ---- pipelined path (full chunk) ----
        f2 rb[PF], vb[PF]; i2 db[PF];
        #pragma unroll
        for (int k = 0; k < PF; ++k) {
            size_t off = (size_t)(e - 1 - k) * N2 + q;
            rb[k] = rw[off];
            vb[k] = vv[off];
            db[k] = __builtin_nontemporal_load(&dn[off]);
        }
        #pragma unroll
        for (int tt = 0; tt < L_; tt += PF) {
            #pragma unroll
            for (int k = 0; k < PF; ++k) {
                int t = e - 1 - tt - k;
                f2 r2 = rb[k]; f2 v2 = vb[k]; i2 d2 = db[k];
                int tp = t - PF;
                if (tp >= s) {                       // refill slot early
                    size_t off = (size_t)tp * N2 + q;
                    rb[k] = rw[off];
                    vb[k] = vv[off];
                    db[k] = __builtin_nontemporal_load(&dn[off]);
                }
                unsigned bit = 1u << (t - s);
                #pragma unroll
                for (int j = 0; j < 2; ++j) {
                    float nt = (d2[j] == 0) ? 1.0f : 0.0f;
                    float delta = r2[j] + GAMMA_ * vnext[j] * nt - v2[j];
                    float c = GL_ * nt;
                    a[j] = delta + c * a[j];
                    P[j] = c * P[j];
                    sa[j]  += a[j];
                    sa2[j] += a[j] * a[j];
                    saP[j] += a[j] * P[j];
                    sP[j]  += P[j];
                    sP2[j] += P[j] * P[j];
                    mm[j] |= (d2[j] == 0) ? bit : 0u;
                    vnext[j] = v2[j];
                }
            }
        }
    } else {
        // ---- generic fallback (partial tail chunk) ----
        for (int t = e - 1; t >= s; --t) {
            size_t off = (size_t)t * N2 + q;
            f2 r2 = rw[off];
            i2 d2 = __builtin_nontemporal_load(&dn[off]);
            f2 v2 = vv[off];
            unsigned bit = 1u << (t - s);
            #pragma unroll
            for (int j = 0; j < 2; ++j) {
                float nt = (d2[j] == 0) ? 1.0f : 0.0f;
                float delta = r2[j] + GAMMA_ * vnext[j] * nt - v2[j];
                float c = GL_ * nt;
                a[j] = delta + c * a[j];
                P[j] = c * P[j];
                sa[j]  += a[j];
                sa2[j] += a[j] * a[j];
                saP[j] += a[j] * P[j];
                sP[j]  += P[j];
                sP2[j] += P[j] * P[j];
                mm[j] |= (d2[j] == 0) ? bit : 0u;
                vnext[j] = v2[j];
            }
        }
    }

    size_t idx = (size_t)chunk * N2 + q;
    f2 o;
    o.x = a[0];   o.y = a[1];   A[idx]   = o;
    o.x = P[0];   o.y = P[1];   B[idx]   = o;
    o.x = sa[0];  o.y = sa[1];  Sa[idx]  = o;
    o.x = sa2[0]; o.y = sa2[1]; Sa2[idx] = o;
    o.x = saP[0]; o.y = saP[1]; SaP[idx] = o;
    o.x = sP[0];  o.y = sP[1];  SP[idx]  = o;
    o.x = sP2[0]; o.y = sP2[1]; SP2[idx] = o;
    u2 om; om.x = mm[0]; om.y = mm[1];
    mask[idx] = om;
}

// ---------------------------------------------------------------------------
// Pass 2 (wave-scan): one wave per column, lane l owns chunk l (C <= 64).
// Affine-map suffix scan in 6 shuffle steps; stats reduced per-wave then
// per-block; 512 atomic pairs total.
// ---------------------------------------------------------------------------
__global__ __launch_bounds__(1024)
void gae_pass2_ws(const float* __restrict__ A, const float* __restrict__ B,
                  const float* __restrict__ Sa, const float* __restrict__ Sa2,
                  const float* __restrict__ SaP, const float* __restrict__ SP,
                  const float* __restrict__ SP2,
                  float* __restrict__ carry, double* __restrict__ sums,
                  int N, int C)
{
    __shared__ double psum[16], psq[16];
    int wid  = threadIdx.x >> 6;
    int lane = threadIdx.x & 63;
    int nwav = blockDim.x >> 6;
    int n = blockIdx.x * nwav + wid;           // column

    float Ah = 0.f, Bh = 1.f;
    float sa = 0.f, sa2 = 0.f, saP = 0.f, sp = 0.f, sp2 = 0.f;
    bool act = (n < N) && (lane < C);
    size_t idx = (size_t)lane * N + n;
    if (act) {
        Ah = A[idx];  Bh = B[idx];
        sa = Sa[idx]; sa2 = Sa2[idx]; saP = SaP[idx];
        sp = SP[idx]; sp2 = SP2[idx];
    }

    // inclusive suffix scan of affine maps: h_l = f_l o f_{l+1} o ... o f_{63}
    #pragma unroll
    for (int d = 1; d < 64; d <<= 1) {
        float Ad = __shfl_down(Ah, d, 64);
        float Bd = __shfl_down(Bh, d, 64);
        if (lane + d < 64) { Ah = fmaf(Bh, Ad, Ah); Bh *= Bd; }
    }
    // carry entering chunk l = h_{l+1}(0)
    float e = __shfl_down(Ah, 1, 64);
    if (lane == 63) e = 0.f;

    double lsum = 0.0, lsq = 0.0;
    if (act) {
        carry[idx] = e;
        lsum = (double)(sa + sp * e);
        lsq  = (double)(sa2 + 2.0f * e * saP + (e * e) * sp2);
    }
    for (int off = 32; off > 0; off >>= 1) {
        lsum += __shfl_down(lsum, off, 64);
        lsq  += __shfl_down(lsq, off, 64);
    }
    if (lane == 0) { psum[wid] = lsum; psq[wid] = lsq; }
    __syncthreads();
    if (threadIdx.x == 0) {
        double s = 0.0, s2 = 0.0;
        for (int w = 0; w < nwav; ++w) { s += psum[w]; s2 += psq[w]; }
        atomicAdd(&sums[0], s);
        atomicAdd(&sums[1], s2);
    }
}

// Fallback sequential pass2 for C > 64 (not hit at T=2048).
__global__ __launch_bounds__(64)
void gae_pass2_seq(const float* __restrict__ A, const float* __restrict__ B,
                   const float* __restrict__ Sa, const float* __restrict__ Sa2,
                   const float* __restrict__ SaP, const float* __restrict__ SP,
                   const float* __restrict__ SP2,
                   float* __restrict__ carry, double* __restrict__ sums,
                   int N, int C)
{
    int n = blockIdx.x * blockDim.x + threadIdx.x;
    double lsum = 0.0, lsq = 0.0;
    if (n < N) {
        float g = 0.f;
        for (int i = C - 1; i >= 0; --i) {
            int idx = i * N + n;
            carry[idx] = g;
            float e = g;
            lsum += (double)(Sa[idx] + SP[idx] * e);
            lsq  += (double)(Sa2[idx] + 2.0f * e * SaP[idx] + (e * e) * SP2[idx]);
            g = A[idx] + B[idx] * g;
        }
    }
    for (int off = 32; off > 0; off >>= 1) {
        lsum += __shfl_down(lsum, off, 64);
        lsq  += __shfl_down(lsq, off, 64);
    }
    if ((threadIdx.x & 63) == 0) {
        atomicAdd(&sums[0], lsum);
        atomicAdd(&sums[1], lsq);
    }
}

// ---------------------------------------------------------------------------
// Pass 3: rescan seeded with the true carry; normalize and emit. Same PF=4
// register pipeline as pass1 (rw,vv only; nt comes from the bitmask).
// Outputs are write-once -> nontemporal stores keep rw/vv LLC-resident.
// ---------------------------------------------------------------------------
__global__ __launch_bounds__(256)
void gae_pass3(const f2* __restrict__ rw, const f2* __restrict__ vv,
               const u2* __restrict__ mask, const f2* __restrict__ carry,
               const double* __restrict__ sums,
               f2* __restrict__ out_adv, f2* __restrict__ out_ret,
               int T, int N2, double Minv, double Mm1inv)
{
    int q = blockIdx.x * blockDim.x + threadIdx.x;
    int chunk = blockIdx.y;
    if (q >= N2) return;
    int s = chunk * L_;
    int e = s + L_; if (e > T) e = T;
    int len = e - s;

    double S = sums[0], S2 = sums[1];
    float mean = (float)(S * Minv);
    double vard = (S2 - S * S * Minv) * Mm1inv;
    float inv = (float)(1.0 / (sqrt(vard) + 1e-8));

    size_t idx = (size_t)chunk * N2 + q;
    f2 c2 = carry[idx];
    u2 m2 = mask[idx];
    float a[2] = {c2.x, c2.y};
    unsigned mm[2] = {m2.x, m2.y};

    f2 vn = vv[(size_t)e * N2 + q];
    float vnext[2] = {vn.x, vn.y};

    if (len == L_) {
        f2 rb[PF], vb[PF];
        #pragma unroll
        for (int k = 0; k < PF; ++k) {
            size_t off = (size_t)(e - 1 - k) * N2 + q;
            rb[k] = rw[off];
            vb[k] = vv[off];
        }
        #pragma unroll
        for (int tt = 0; tt < L_; tt += PF) {
            #pragma unroll
            for (int k = 0; k < PF; ++k) {
                int t = e - 1 - tt - k;
                f2 r2 = rb[k]; f2 v2 = vb[k];
                int tp = t - PF;
                if (tp >= s) {
                    size_t off = (size_t)tp * N2 + q;
                    rb[k] = rw[off];
                    vb[k] = vv[off];
                }
                unsigned bit = 1u << (t - s);
                size_t off = (size_t)t * N2 + q;
                f2 oa, orr;
                #pragma unroll
                for (int j = 0; j < 2; ++j) {
                    float nt = (mm[j] & bit) ? 1.0f : 0.0f;
                    float delta = r2[j] + GAMMA_ * vnext[j] * nt - v2[j];
                    a[j] = delta + GL_ * nt * a[j];
                    oa[j]  = (a[j] - mean) * inv;
                    orr[j] = a[j] + v2[j];
                    vnext[j] = v2[j];
                }
                __builtin_nontemporal_store(oa,  &out_adv[off]);
                __builtin_nontemporal_store(orr, &out_ret[off]);
            }
        }
    } else {
        for (int t = e - 1; t >= s; --t) {
            size_t off = (size_t)t * N2 + q;
            f2 r2 = rw[off];
            f2 v2 = vv[off];
            unsigned bit = 1u << (t - s);
            f2 oa, orr;
            #pragma unroll
            for (int j = 0; j < 2; ++j) {
                float nt = (mm[j] & bit) ? 1.0f : 0.0f;
                float delta = r2[j] + GAMMA_ * vnext[j] * nt - v2[j];
                a[j] = delta + GL_ * nt * a[j];
                oa[j]  = (a[j] - mean) * inv;
                orr[j] = a[j] + v2[j];
                vnext[j] = v2[j];
            }
            __builtin_nontemporal_store(oa,  &out_adv[off]);
            __builtin_nontemporal_store(orr, &out_ret[off]);
        }
    }
}

extern "C" void kernel_launch(void* const* d_in, const int* in_sizes, int n_in,
                              void* d_out, int out_size, void* d_ws, size_t ws_size,
                              hipStream_t stream)
{
    const float* rw = (const float*)d_in[0];
    const float* vv = (const float*)d_in[1];
    const int*   dn = (const int*)d_in[2];

    long long TN = in_sizes[0];          // T*N
    long long VN = in_sizes[1];          // (T+1)*N
    int N = (int)(VN - TN);
    int T = (int)(TN / N);
    int N2 = N / 2;
    int C = (T + L_ - 1) / L_;           // 64 for T=2048

    // Workspace: [2 doubles][mask: C*N u32][8 float arrays of C*N]
    char* ws = (char*)d_ws;
    double* sums = (double*)ws;
    size_t cn = (size_t)C * N;
    unsigned* mask = (unsigned*)(ws + 16);
    float* f   = (float*)(ws + 16 + cn * 4);
    float* A   = f;
    float* B   = f + cn;
    float* Sa  = f + 2 * cn;
    float* Sa2 = f + 3 * cn;
    float* SaP = f + 4 * cn;
    float* SP  = f + 5 * cn;
    float* SP2 = f + 6 * cn;
    float* cry = f + 7 * cn;

    dim3 blk(256);
    dim3 g1((N2 + 255) / 256, C);
    gae_pass1<<<g1, blk, 0, stream>>>(
        (const f2*)rw, (const f2*)vv, (const i2*)dn,
        (f2*)A, (f2*)B, (f2*)Sa, (f2*)Sa2, (f2*)SaP,
        (f2*)SP, (f2*)SP2, (u2*)mask, sums, T, N2);

    if (C <= 64) {
        int wpb = 16;                    // waves (columns) per block
        gae_pass2_ws<<<dim3((N + wpb - 1) / wpb), dim3(wpb * 64), 0, stream>>>(
            A, B, Sa, Sa2, SaP, SP, SP2, cry, sums, N, C);
    } else {
        gae_pass2_seq<<<dim3((N + 63) / 64), dim3(64), 0, stream>>>(
            A, B, Sa, Sa2, SaP, SP, SP2, cry, sums, N, C);
    }

    double M = (double)TN;
    gae_pass3<<<g1, blk, 0, stream>>>(
        (const f2*)rw, (const f2*)vv, (const u2*)mask,
        (const f2*)cry, sums,
        (f2*)d_out, (f2*)((float*)d_out + TN),
        T, N2, 1.0 / M, 1.0 / (M - 1.0));
}

// Round 3
// 314.722 us; speedup vs baseline: 1.1282x; 1.1282x over previous
//
#include <hip/hip_runtime.h>
#include <math.h>

#define GAMMA_ 0.99f
#define GL_ (0.99f * 0.95f)
#define L_ 32            // chunk length (mask fits in u32)

// ---------------------------------------------------------------------------
// Pass 1: one COLUMN per thread, one chunk per blockIdx.y. The entire
// 32-step chunk is loaded into registers as ONE flat batch of 97
// independent dword loads (32 r + 33 v + 32 d, fully unrolled, no control
// flow between loads) and only then scanned serially from registers.
// Rationale (round-2 post-mortem): a rotated PF-slot pipeline let the
// scheduler interleave refills with uses -> loads re-serialized behind
// per-iteration waitcnts (BW 1.1 TB/s, VGPR 192). A flat batch has no use
// between loads, so the compiler must issue them back-to-back: ~16-25 KB
// in flight per wave -> BW-bound even at 8 waves/CU.
// Emits per-chunk affine summary (A,B), stats, and a nonterminal bitmask.
// Thread (0,0,0) zeroes the double accumulators (replaces hipMemsetAsync).
// ---------------------------------------------------------------------------
__global__ __launch_bounds__(256)
void gae_pass1(const float* __restrict__ rw, const float* __restrict__ vv,
               const int* __restrict__ dn,
               float* __restrict__ A, float* __restrict__ B,
               float* __restrict__ Sa, float* __restrict__ Sa2,
               float* __restrict__ SaP, float* __restrict__ SP,
               float* __restrict__ SP2, unsigned* __restrict__ mask,
               double* __restrict__ sums,
               int T, int N)
{
    if (blockIdx.x == 0 && blockIdx.y == 0 && threadIdx.x == 0) {
        sums[0] = 0.0; sums[1] = 0.0;
    }
    int n = blockIdx.x * blockDim.x + threadIdx.x;   // column
    int chunk = blockIdx.y;
    if (n >= N) return;
    int s = chunk * L_;
    int e = s + L_; if (e > T) e = T;
    int len = e - s;

    float a = 0.f, P = 1.f;
    float sa = 0.f, sa2 = 0.f, saP = 0.f, sP = 0.f, sP2 = 0.f;
    unsigned mm = 0u;

    if (len == L_) {
        // ---- flat batch load: 97 independent loads, no uses in between ----
        float r[L_], v[L_ + 1];
        int   d[L_];
        #pragma unroll
        for (int k = 0; k < L_; ++k)
            r[k] = rw[(size_t)(s + k) * N + n];
        #pragma unroll
        for (int k = 0; k <= L_; ++k)
            v[k] = vv[(size_t)(s + k) * N + n];
        #pragma unroll
        for (int k = 0; k < L_; ++k)
            d[k] = __builtin_nontemporal_load(&dn[(size_t)(s + k) * N + n]);

        // ---- serial scan purely from registers (k = t - s, descending) ----
        #pragma unroll
        for (int k = L_ - 1; k >= 0; --k) {
            float nt = (d[k] == 0) ? 1.0f : 0.0f;
            float delta = r[k] + GAMMA_ * v[k + 1] * nt - v[k];
            float c = GL_ * nt;
            a = delta + c * a;
            P = c * P;
            sa  += a;
            sa2 += a * a;
            saP += a * P;
            sP  += P;
            sP2 += P * P;
            mm |= (d[k] == 0) ? (1u << k) : 0u;
        }
    } else {
        // ---- generic fallback (partial tail chunk) ----
        float vnext = vv[(size_t)e * N + n];
        for (int t = e - 1; t >= s; --t) {
            size_t off = (size_t)t * N + n;
            float r = rw[off];
            int   dd = dn[off];
            float vc = vv[off];
            float nt = (dd == 0) ? 1.0f : 0.0f;
            float delta = r + GAMMA_ * vnext * nt - vc;
            float c = GL_ * nt;
            a = delta + c * a;
            P = c * P;
            sa  += a;
            sa2 += a * a;
            saP += a * P;
            sP  += P;
            sP2 += P * P;
            mm |= (dd == 0) ? (1u << (t - s)) : 0u;
            vnext = vc;
        }
    }

    size_t idx = (size_t)chunk * N + n;
    A[idx]   = a;
    B[idx]   = P;
    Sa[idx]  = sa;
    Sa2[idx] = sa2;
    SaP[idx] = saP;
    SP[idx]  = sP;
    SP2[idx] = sP2;
    mask[idx] = mm;
}

// ---------------------------------------------------------------------------
// Pass 2 (wave-scan): one wave per column, lane l owns chunk l (C <= 64).
// Affine-map suffix scan in 6 shuffle steps; stats reduced per-wave then
// per-block; 512 atomic pairs total.
// ---------------------------------------------------------------------------
__global__ __launch_bounds__(1024)
void gae_pass2_ws(const float* __restrict__ A, const float* __restrict__ B,
                  const float* __restrict__ Sa, const float* __restrict__ Sa2,
                  const float* __restrict__ SaP, const float* __restrict__ SP,
                  const float* __restrict__ SP2,
                  float* __restrict__ carry, double* __restrict__ sums,
                  int N, int C)
{
    __shared__ double psum[16], psq[16];
    int wid  = threadIdx.x >> 6;
    int lane = threadIdx.x & 63;
    int nwav = blockDim.x >> 6;
    int n = blockIdx.x * nwav + wid;           // column

    float Ah = 0.f, Bh = 1.f;
    float sa = 0.f, sa2 = 0.f, saP = 0.f, sp = 0.f, sp2 = 0.f;
    bool act = (n < N) && (lane < C);
    size_t idx = (size_t)lane * N + n;
    if (act) {
        Ah = A[idx];  Bh = B[idx];
        sa = Sa[idx]; sa2 = Sa2[idx]; saP = SaP[idx];
        sp = SP[idx]; sp2 = SP2[idx];
    }

    // inclusive suffix scan of affine maps: h_l = f_l o f_{l+1} o ... o f_{63}
    #pragma unroll
    for (int d = 1; d < 64; d <<= 1) {
        float Ad = __shfl_down(Ah, d, 64);
        float Bd = __shfl_down(Bh, d, 64);
        if (lane + d < 64) { Ah = fmaf(Bh, Ad, Ah); Bh *= Bd; }
    }
    // carry entering chunk l = h_{l+1}(0)
    float e = __shfl_down(Ah, 1, 64);
    if (lane == 63) e = 0.f;

    double lsum = 0.0, lsq = 0.0;
    if (act) {
        carry[idx] = e;
        lsum = (double)(sa + sp * e);
        lsq  = (double)(sa2 + 2.0f * e * saP + (e * e) * sp2);
    }
    for (int off = 32; off > 0; off >>= 1) {
        lsum += __shfl_down(lsum, off, 64);
        lsq  += __shfl_down(lsq, off, 64);
    }
    if (lane == 0) { psum[wid] = lsum; psq[wid] = lsq; }
    __syncthreads();
    if (threadIdx.x == 0) {
        double s = 0.0, s2 = 0.0;
        for (int w = 0; w < nwav; ++w) { s += psum[w]; s2 += psq[w]; }
        atomicAdd(&sums[0], s);
        atomicAdd(&sums[1], s2);
    }
}

// Fallback sequential pass2 for C > 64 (not hit at T=2048).
__global__ __launch_bounds__(64)
void gae_pass2_seq(const float* __restrict__ A, const float* __restrict__ B,
                   const float* __restrict__ Sa, const float* __restrict__ Sa2,
                   const float* __restrict__ SaP, const float* __restrict__ SP,
                   const float* __restrict__ SP2,
                   float* __restrict__ carry, double* __restrict__ sums,
                   int N, int C)
{
    int n = blockIdx.x * blockDim.x + threadIdx.x;
    double lsum = 0.0, lsq = 0.0;
    if (n < N) {
        float g = 0.f;
        for (int i = C - 1; i >= 0; --i) {
            int idx = i * N + n;
            carry[idx] = g;
            float e = g;
            lsum += (double)(Sa[idx] + SP[idx] * e);
            lsq  += (double)(Sa2[idx] + 2.0f * e * SaP[idx] + (e * e) * SP2[idx]);
            g = A[idx] + B[idx] * g;
        }
    }
    for (int off = 32; off > 0; off >>= 1) {
        lsum += __shfl_down(lsum, off, 64);
        lsq  += __shfl_down(lsq, off, 64);
    }
    if ((threadIdx.x & 63) == 0) {
        atomicAdd(&sums[0], lsum);
        atomicAdd(&sums[1], lsq);
    }
}

// ---------------------------------------------------------------------------
// Pass 3: same flat-batch structure (65 loads: 32 r + 33 v), scan seeded
// with the true carry, normalize, emit via nontemporal stores (write-once
// data; keeps rw/vv LLC-resident for the next bench iteration).
// ---------------------------------------------------------------------------
__global__ __launch_bounds__(256)
void gae_pass3(const float* __restrict__ rw, const float* __restrict__ vv,
               const unsigned* __restrict__ mask, const float* __restrict__ carry,
               const double* __restrict__ sums,
               float* __restrict__ out_adv, float* __restrict__ out_ret,
               int T, int N, double Minv, double Mm1inv)
{
    int n = blockIdx.x * blockDim.x + threadIdx.x;
    int chunk = blockIdx.y;
    if (n >= N) return;
    int s = chunk * L_;
    int e = s + L_; if (e > T) e = T;
    int len = e - s;

    double S = sums[0], S2 = sums[1];
    float mean = (float)(S * Minv);
    double vard = (S2 - S * S * Minv) * Mm1inv;
    float inv = (float)(1.0 / (sqrt(vard) + 1e-8));

    size_t idx = (size_t)chunk * N + n;
    float a = carry[idx];
    unsigned mm = mask[idx];

    if (len == L_) {
        // ---- flat batch load: 65 independent loads ----
        float r[L_], v[L_ + 1];
        #pragma unroll
        for (int k = 0; k < L_; ++k)
            r[k] = rw[(size_t)(s + k) * N + n];
        #pragma unroll
        for (int k = 0; k <= L_; ++k)
            v[k] = vv[(size_t)(s + k) * N + n];

        #pragma unroll
        for (int k = L_ - 1; k >= 0; --k) {
            float nt = (mm & (1u << k)) ? 1.0f : 0.0f;
            float delta = r[k] + GAMMA_ * v[k + 1] * nt - v[k];
            a = delta + GL_ * nt * a;
            size_t off = (size_t)(s + k) * N + n;
            __builtin_nontemporal_store((a - mean) * inv, &out_adv[off]);
            __builtin_nontemporal_store(a + v[k],        &out_ret[off]);
        }
    } else {
        float vnext = vv[(size_t)e * N + n];
        for (int t = e - 1; t >= s; --t) {
            size_t off = (size_t)t * N + n;
            float r = rw[off];
            float vc = vv[off];
            float nt = (mm & (1u << (t - s))) ? 1.0f : 0.0f;
            float delta = r + GAMMA_ * vnext * nt - vc;
            a = delta + GL_ * nt * a;
            __builtin_nontemporal_store((a - mean) * inv, &out_adv[off]);
            __builtin_nontemporal_store(a + vc,          &out_ret[off]);
            vnext = vc;
        }
    }
}

extern "C" void kernel_launch(void* const* d_in, const int* in_sizes, int n_in,
                              void* d_out, int out_size, void* d_ws, size_t ws_size,
                              hipStream_t stream)
{
    const float* rw = (const float*)d_in[0];
    const float* vv = (const float*)d_in[1];
    const int*   dn = (const int*)d_in[2];

    long long TN = in_sizes[0];          // T*N
    long long VN = in_sizes[1];          // (T+1)*N
    int N = (int)(VN - TN);
    int T = (int)(TN / N);
    int C = (T + L_ - 1) / L_;           // 64 for T=2048

    // Workspace: [2 doubles][mask: C*N u32][8 float arrays of C*N]
    char* ws = (char*)d_ws;
    double* sums = (double*)ws;
    size_t cn = (size_t)C * N;
    unsigned* mask = (unsigned*)(ws + 16);
    float* f   = (float*)(ws + 16 + cn * 4);
    float* A   = f;
    float* B   = f + cn;
    float* Sa  = f + 2 * cn;
    float* Sa2 = f + 3 * cn;
    float* SaP = f + 4 * cn;
    float* SP  = f + 5 * cn;
    float* SP2 = f + 6 * cn;
    float* cry = f + 7 * cn;

    dim3 blk(256);
    dim3 g1((N + 255) / 256, C);
    gae_pass1<<<g1, blk, 0, stream>>>(
        rw, vv, dn, A, B, Sa, Sa2, SaP, SP, SP2, mask, sums, T, N);

    if (C <= 64) {
        int wpb = 16;                    // waves (columns) per block
        gae_pass2_ws<<<dim3((N + wpb - 1) / wpb), dim3(wpb * 64), 0, stream>>>(
            A, B, Sa, Sa2, SaP, SP, SP2, cry, sums, N, C);
    } else {
        gae_pass2_seq<<<dim3((N + 63) / 64), dim3(64), 0, stream>>>(
            A, B, Sa, Sa2, SaP, SP, SP2, cry, sums, N, C);
    }

    double M = (double)TN;
    gae_pass3<<<g1, blk, 0, stream>>>(
        rw, vv, mask, cry, sums,
        (float*)d_out, (float*)d_out + TN,
        T, N, 1.0 / M, 1.0 / (M - 1.0));
}

// Round 4
// 312.304 us; speedup vs baseline: 1.1370x; 1.0077x over previous
//
#include <hip/hip_runtime.h>
#include <hip/hip_cooperative_groups.h>
#include <math.h>

namespace cg = cooperative_groups;

#define GAMMA_ 0.99f
#define GL_ (0.99f * 0.95f)
#define L_ 32            // fallback-path chunk length (mask fits in u32)
#define LF_ 64           // fused-path steps per thread (mask fits in u64)
#define GF_ 16           // fused-path flat-group load depth

// ===========================================================================
// FUSED cooperative kernel: all three phases in one launch.
// Thread = (column n, 64-step chunk c). v[65] and the nonterminal mask live
// in REGISTERS across the grid syncs -> pass3's 67 MB v re-read and the
// mask round-trip disappear, as do 2 kernel-launch gaps.
//   phase1: load v (65-load burst), stream r,d in 16-deep flat groups,
//           local scan -> per-chunk affine (A,B) + stats to global.
//   phase2: per-column suffix scan of 32 affine maps (width-32 shuffles,
//           2 columns/wave), carry to global, stats -> f64 atomics.
//   phase3: re-load r only (L3-warm), reuse register v/mask, NT stores.
// Geometry: C2*N threads, 256/block; __launch_bounds__(256,4) caps VGPR at
// 128 so 4 blocks/CU -> exactly 1024 co-resident blocks at T=2048,N=8192.
// ===========================================================================
__global__ __launch_bounds__(256, 4)
void gae_fused(const float* __restrict__ rw, const float* __restrict__ vv,
               const int* __restrict__ dn,
               float* __restrict__ A, float* __restrict__ B,
               float* __restrict__ Sa, float* __restrict__ Sa2,
               float* __restrict__ SaP, float* __restrict__ SP,
               float* __restrict__ SP2, float* __restrict__ carry,
               double* __restrict__ sums,
               float* __restrict__ out_adv, float* __restrict__ out_ret,
               int T, int N, int C2, double Minv, double Mm1inv)
{
    int gtid = blockIdx.x * blockDim.x + threadIdx.x;
    int n = gtid % N;            // column
    int c = gtid / N;            // 64-step chunk index, c in [0, C2)
    int s = c * LF_;
    if (gtid == 0) { sums[0] = 0.0; sums[1] = 0.0; }

    // ---------------- phase 1: local scan, summaries ----------------
    float v[LF_ + 1];
    #pragma unroll
    for (int k = 0; k <= LF_; ++k)
        v[k] = vv[(size_t)(s + k) * N + n];

    float a = 0.f, P = 1.f;
    float sa = 0.f, sa2 = 0.f, saP = 0.f, sP = 0.f, sP2 = 0.f;
    unsigned long long mm = 0ull;

    #pragma unroll
    for (int g = LF_ / GF_ - 1; g >= 0; --g) {
        float r[GF_]; int d[GF_];
        #pragma unroll
        for (int i = 0; i < GF_; ++i)
            r[i] = rw[(size_t)(s + g * GF_ + i) * N + n];
        #pragma unroll
        for (int i = 0; i < GF_; ++i)
            d[i] = __builtin_nontemporal_load(&dn[(size_t)(s + g * GF_ + i) * N + n]);
        #pragma unroll
        for (int i = GF_ - 1; i >= 0; --i) {
            int k = g * GF_ + i;
            float nt = (d[i] == 0) ? 1.f : 0.f;
            float delta = r[i] + GAMMA_ * v[k + 1] * nt - v[k];
            float cc = GL_ * nt;
            a = delta + cc * a;
            P = cc * P;
            sa += a; sa2 += a * a; saP += a * P; sP += P; sP2 += P * P;
            mm |= (d[i] == 0) ? (1ull << k) : 0ull;
        }
    }
    size_t idx = (size_t)c * N + n;
    A[idx] = a;  B[idx] = P;
    Sa[idx] = sa; Sa2[idx] = sa2; SaP[idx] = saP; SP[idx] = sP; SP2[idx] = sP2;

    __threadfence();
    cg::this_grid().sync();

    // ---------------- phase 2: cross-chunk scan + global stats ----------------
    {
        int wglob = blockIdx.x * (blockDim.x >> 6) + (threadIdx.x >> 6);
        int totw  = gridDim.x * (blockDim.x >> 6);
        int lane = threadIdx.x & 63, half = lane >> 5, lh = lane & 31;
        for (int base = wglob * 2; base < N; base += totw * 2) {
            int col = base + half;
            bool act = (col < N) && (lh < C2);
            size_t i2 = (size_t)lh * N + col;
            float Ah = 0.f, Bh = 1.f;
            float psa = 0.f, psa2 = 0.f, psaP = 0.f, psP = 0.f, psP2 = 0.f;
            if (act) {
                Ah = A[i2]; Bh = B[i2];
                psa = Sa[i2]; psa2 = Sa2[i2]; psaP = SaP[i2];
                psP = SP[i2]; psP2 = SP2[i2];
            }
            // suffix scan of affine maps within the 32-lane half
            #pragma unroll
            for (int dd = 1; dd < 32; dd <<= 1) {
                float Ad = __shfl_down(Ah, dd, 32);
                float Bd = __shfl_down(Bh, dd, 32);
                if (lh + dd < 32) { Ah = fmaf(Bh, Ad, Ah); Bh *= Bd; }
            }
            float e = __shfl_down(Ah, 1, 32);
            if (lh == 31) e = 0.f;
            double lsum = 0.0, lsq = 0.0;
            if (act) {
                carry[i2] = e;
                lsum = (double)(psa + psP * e);
                lsq  = (double)(psa2 + 2.f * e * psaP + (e * e) * psP2);
            }
            for (int off = 32; off > 0; off >>= 1) {
                lsum += __shfl_down(lsum, off, 64);
                lsq  += __shfl_down(lsq, off, 64);
            }
            if (lane == 0) { atomicAdd(&sums[0], lsum); atomicAdd(&sums[1], lsq); }
        }
    }

    __threadfence();
    cg::this_grid().sync();

    // ---------------- phase 3: rescan with true carry, emit ----------------
    double S = sums[0], S2 = sums[1];
    float mean = (float)(S * Minv);
    double vard = (S2 - S * S * Minv) * Mm1inv;
    float inv = (float)(1.0 / (sqrt(vard) + 1e-8));

    a = carry[idx];
    #pragma unroll
    for (int g = LF_ / GF_ - 1; g >= 0; --g) {
        float r[GF_];
        #pragma unroll
        for (int i = 0; i < GF_; ++i)
            r[i] = rw[(size_t)(s + g * GF_ + i) * N + n];
        #pragma unroll
        for (int i = GF_ - 1; i >= 0; --i) {
            int k = g * GF_ + i;
            float nt = (mm & (1ull << k)) ? 1.f : 0.f;
            float delta = r[i] + GAMMA_ * v[k + 1] * nt - v[k];
            a = delta + GL_ * nt * a;
            size_t off = (size_t)(s + k) * N + n;
            __builtin_nontemporal_store((a - mean) * inv, &out_adv[off]);
            __builtin_nontemporal_store(a + v[k],         &out_ret[off]);
        }
    }
}

// ===========================================================================
// FALLBACK path: round-3's verified three-kernel pipeline (used if the
// cooperative geometry doesn't fit or the shape is irregular).
// ===========================================================================
__global__ __launch_bounds__(256)
void gae_pass1(const float* __restrict__ rw, const float* __restrict__ vv,
               const int* __restrict__ dn,
               float* __restrict__ A, float* __restrict__ B,
               float* __restrict__ Sa, float* __restrict__ Sa2,
               float* __restrict__ SaP, float* __restrict__ SP,
               float* __restrict__ SP2, unsigned* __restrict__ mask,
               double* __restrict__ sums,
               int T, int N)
{
    if (blockIdx.x == 0 && blockIdx.y == 0 && threadIdx.x == 0) {
        sums[0] = 0.0; sums[1] = 0.0;
    }
    int n = blockIdx.x * blockDim.x + threadIdx.x;
    int chunk = blockIdx.y;
    if (n >= N) return;
    int s = chunk * L_;
    int e = s + L_; if (e > T) e = T;
    int len = e - s;

    float a = 0.f, P = 1.f;
    float sa = 0.f, sa2 = 0.f, saP = 0.f, sP = 0.f, sP2 = 0.f;
    unsigned mm = 0u;

    if (len == L_) {
        float r[L_], v[L_ + 1];
        int   d[L_];
        #pragma unroll
        for (int k = 0; k < L_; ++k)
            r[k] = rw[(size_t)(s + k) * N + n];
        #pragma unroll
        for (int k = 0; k <= L_; ++k)
            v[k] = vv[(size_t)(s + k) * N + n];
        #pragma unroll
        for (int k = 0; k < L_; ++k)
            d[k] = __builtin_nontemporal_load(&dn[(size_t)(s + k) * N + n]);

        #pragma unroll
        for (int k = L_ - 1; k >= 0; --k) {
            float nt = (d[k] == 0) ? 1.0f : 0.0f;
            float delta = r[k] + GAMMA_ * v[k + 1] * nt - v[k];
            float c = GL_ * nt;
            a = delta + c * a;
            P = c * P;
            sa += a; sa2 += a * a; saP += a * P; sP += P; sP2 += P * P;
            mm |= (d[k] == 0) ? (1u << k) : 0u;
        }
    } else {
        float vnext = vv[(size_t)e * N + n];
        for (int t = e - 1; t >= s; --t) {
            size_t off = (size_t)t * N + n;
            float r = rw[off];
            int   dd = dn[off];
            float vc = vv[off];
            float nt = (dd == 0) ? 1.0f : 0.0f;
            float delta = r + GAMMA_ * vnext * nt - vc;
            float c = GL_ * nt;
            a = delta + c * a;
            P = c * P;
            sa += a; sa2 += a * a; saP += a * P; sP += P; sP2 += P * P;
            mm |= (dd == 0) ? (1u << (t - s)) : 0u;
            vnext = vc;
        }
    }

    size_t idx = (size_t)chunk * N + n;
    A[idx] = a;  B[idx] = P;
    Sa[idx] = sa; Sa2[idx] = sa2; SaP[idx] = saP; SP[idx] = sP; SP2[idx] = sP2;
    mask[idx] = mm;
}

__global__ __launch_bounds__(1024)
void gae_pass2_ws(const float* __restrict__ A, const float* __restrict__ B,
                  const float* __restrict__ Sa, const float* __restrict__ Sa2,
                  const float* __restrict__ SaP, const float* __restrict__ SP,
                  const float* __restrict__ SP2,
                  float* __restrict__ carry, double* __restrict__ sums,
                  int N, int C)
{
    __shared__ double psum[16], psq[16];
    int wid  = threadIdx.x >> 6;
    int lane = threadIdx.x & 63;
    int nwav = blockDim.x >> 6;
    int n = blockIdx.x * nwav + wid;

    float Ah = 0.f, Bh = 1.f;
    float sa = 0.f, sa2 = 0.f, saP = 0.f, sp = 0.f, sp2 = 0.f;
    bool act = (n < N) && (lane < C);
    size_t idx = (size_t)lane * N + n;
    if (act) {
        Ah = A[idx];  Bh = B[idx];
        sa = Sa[idx]; sa2 = Sa2[idx]; saP = SaP[idx];
        sp = SP[idx]; sp2 = SP2[idx];
    }
    #pragma unroll
    for (int d = 1; d < 64; d <<= 1) {
        float Ad = __shfl_down(Ah, d, 64);
        float Bd = __shfl_down(Bh, d, 64);
        if (lane + d < 64) { Ah = fmaf(Bh, Ad, Ah); Bh *= Bd; }
    }
    float e = __shfl_down(Ah, 1, 64);
    if (lane == 63) e = 0.f;

    double lsum = 0.0, lsq = 0.0;
    if (act) {
        carry[idx] = e;
        lsum = (double)(sa + sp * e);
        lsq  = (double)(sa2 + 2.0f * e * saP + (e * e) * sp2);
    }
    for (int off = 32; off > 0; off >>= 1) {
        lsum += __shfl_down(lsum, off, 64);
        lsq  += __shfl_down(lsq, off, 64);
    }
    if (lane == 0) { psum[wid] = lsum; psq[wid] = lsq; }
    __syncthreads();
    if (threadIdx.x == 0) {
        double s = 0.0, s2 = 0.0;
        for (int w = 0; w < nwav; ++w) { s += psum[w]; s2 += psq[w]; }
        atomicAdd(&sums[0], s);
        atomicAdd(&sums[1], s2);
    }
}

__global__ __launch_bounds__(64)
void gae_pass2_seq(const float* __restrict__ A, const float* __restrict__ B,
                   const float* __restrict__ Sa, const float* __restrict__ Sa2,
                   const float* __restrict__ SaP, const float* __restrict__ SP,
                   const float* __restrict__ SP2,
                   float* __restrict__ carry, double* __restrict__ sums,
                   int N, int C)
{
    int n = blockIdx.x * blockDim.x + threadIdx.x;
    double lsum = 0.0, lsq = 0.0;
    if (n < N) {
        float g = 0.f;
        for (int i = C - 1; i >= 0; --i) {
            int idx = i * N + n;
            carry[idx] = g;
            float e = g;
            lsum += (double)(Sa[idx] + SP[idx] * e);
            lsq  += (double)(Sa2[idx] + 2.0f * e * SaP[idx] + (e * e) * SP2[idx]);
            g = A[idx] + B[idx] * g;
        }
    }
    for (int off = 32; off > 0; off >>= 1) {
        lsum += __shfl_down(lsum, off, 64);
        lsq  += __shfl_down(lsq, off, 64);
    }
    if ((threadIdx.x & 63) == 0) {
        atomicAdd(&sums[0], lsum);
        atomicAdd(&sums[1], lsq);
    }
}

__global__ __launch_bounds__(256)
void gae_pass3(const float* __restrict__ rw, const float* __restrict__ vv,
               const unsigned* __restrict__ mask, const float* __restrict__ carry,
               const double* __restrict__ sums,
               float* __restrict__ out_adv, float* __restrict__ out_ret,
               int T, int N, double Minv, double Mm1inv)
{
    int n = blockIdx.x * blockDim.x + threadIdx.x;
    int chunk = blockIdx.y;
    if (n >= N) return;
    int s = chunk * L_;
    int e = s + L_; if (e > T) e = T;
    int len = e - s;

    double S = sums[0], S2 = sums[1];
    float mean = (float)(S * Minv);
    double vard = (S2 - S * S * Minv) * Mm1inv;
    float inv = (float)(1.0 / (sqrt(vard) + 1e-8));

    size_t idx = (size_t)chunk * N + n;
    float a = carry[idx];
    unsigned mm = mask[idx];

    if (len == L_) {
        float r[L_], v[L_ + 1];
        #pragma unroll
        for (int k = 0; k < L_; ++k)
            r[k] = rw[(size_t)(s + k) * N + n];
        #pragma unroll
        for (int k = 0; k <= L_; ++k)
            v[k] = vv[(size_t)(s + k) * N + n];

        #pragma unroll
        for (int k = L_ - 1; k >= 0; --k) {
            float nt = (mm & (1u << k)) ? 1.0f : 0.0f;
            float delta = r[k] + GAMMA_ * v[k + 1] * nt - v[k];
            a = delta + GL_ * nt * a;
            size_t off = (size_t)(s + k) * N + n;
            __builtin_nontemporal_store((a - mean) * inv, &out_adv[off]);
            __builtin_nontemporal_store(a + v[k],        &out_ret[off]);
        }
    } else {
        float vnext = vv[(size_t)e * N + n];
        for (int t = e - 1; t >= s; --t) {
            size_t off = (size_t)t * N + n;
            float r = rw[off];
            float vc = vv[off];
            float nt = (mm & (1u << (t - s))) ? 1.0f : 0.0f;
            float delta = r + GAMMA_ * vnext * nt - vc;
            a = delta + GL_ * nt * a;
            __builtin_nontemporal_store((a - mean) * inv, &out_adv[off]);
            __builtin_nontemporal_store(a + vc,          &out_ret[off]);
            vnext = vc;
        }
    }
}

extern "C" void kernel_launch(void* const* d_in, const int* in_sizes, int n_in,
                              void* d_out, int out_size, void* d_ws, size_t ws_size,
                              hipStream_t stream)
{
    const float* rw = (const float*)d_in[0];
    const float* vv = (const float*)d_in[1];
    const int*   dn = (const int*)d_in[2];

    long long TN = in_sizes[0];          // T*N
    long long VN = in_sizes[1];          // (T+1)*N
    int N = (int)(VN - TN);
    int T = (int)(TN / N);
    double M = (double)TN;
    double Minv = 1.0 / M, Mm1inv = 1.0 / (M - 1.0);

    float* out_adv = (float*)d_out;
    float* out_ret = (float*)d_out + TN;

    // ---- fused cooperative path ----
    int C2 = T / LF_;
    long long units = (long long)C2 * N;
    bool fast = (T % LF_ == 0) && (C2 >= 1) && (C2 <= 32) && (units % 256 == 0);
    int nblk = fast ? (int)(units / 256) : 0;

    static int s_cap = -1;               // total co-resident block capacity
    if (fast) {
        if (s_cap < 0) {
            int dev = 0; hipGetDevice(&dev);
            int ncu = 0;
            hipDeviceGetAttribute(&ncu, hipDeviceAttributeMultiprocessorCount, dev);
            int perCU = 0;
            hipOccupancyMaxActiveBlocksPerMultiprocessor(&perCU, gae_fused, 256, 0);
            s_cap = (ncu > 0 && perCU > 0) ? ncu * perCU : 0;
        }
        if (nblk > s_cap) fast = false;
    }

    char* ws = (char*)d_ws;
    double* sums = (double*)ws;

    if (fast) {
        size_t cn = (size_t)C2 * N;
        float* f   = (float*)(ws + 16);
        float* A   = f;
        float* B   = f + cn;
        float* Sa  = f + 2 * cn;
        float* Sa2 = f + 3 * cn;
        float* SaP = f + 4 * cn;
        float* SP  = f + 5 * cn;
        float* SP2 = f + 6 * cn;
        float* cry = f + 7 * cn;

        void* args[] = {
            (void*)&rw, (void*)&vv, (void*)&dn,
            (void*)&A, (void*)&B, (void*)&Sa, (void*)&Sa2, (void*)&SaP,
            (void*)&SP, (void*)&SP2, (void*)&cry, (void*)&sums,
            (void*)&out_adv, (void*)&out_ret,
            (void*)&T, (void*)&N, (void*)&C2, (void*)&Minv, (void*)&Mm1inv
        };
        hipError_t err = hipLaunchCooperativeKernel(
            (void*)gae_fused, dim3(nblk), dim3(256), args, 0, stream);
        if (err == hipSuccess) return;
        // else fall through to the 3-kernel path
    }

    // ---- fallback: three-kernel pipeline (round-3 verified) ----
    int C = (T + L_ - 1) / L_;
    size_t cn = (size_t)C * N;
    unsigned* mask = (unsigned*)(ws + 16);
    float* f   = (float*)(ws + 16 + cn * 4);
    float* A   = f;
    float* B   = f + cn;
    float* Sa  = f + 2 * cn;
    float* Sa2 = f + 3 * cn;
    float* SaP = f + 4 * cn;
    float* SP  = f + 5 * cn;
    float* SP2 = f + 6 * cn;
    float* cry = f + 7 * cn;

    dim3 blk(256);
    dim3 g1((N + 255) / 256, C);
    gae_pass1<<<g1, blk, 0, stream>>>(
        rw, vv, dn, A, B, Sa, Sa2, SaP, SP, SP2, mask, sums, T, N);

    if (C <= 64) {
        int wpb = 16;
        gae_pass2_ws<<<dim3((N + wpb - 1) / wpb), dim3(wpb * 64), 0, stream>>>(
            A, B, Sa, Sa2, SaP, SP, SP2, cry, sums, N, C);
    } else {
        gae_pass2_seq<<<dim3((N + 63) / 64), dim3(64), 0, stream>>>(
            A, B, Sa, Sa2, SaP, SP, SP2, cry, sums, N, C);
    }

    gae_pass3<<<g1, blk, 0, stream>>>(
        rw, vv, mask, cry, sums, out_adv, out_ret, T, N, Minv, Mm1inv);
}

// Round 5
// 307.601 us; speedup vs baseline: 1.1544x; 1.0153x over previous
//
#include <hip/hip_runtime.h>
#include <math.h>

#define GAMMA_ 0.99f
#define GL_ (0.99f * 0.95f)
#define L_ 32            // chunk length (mask fits in u32)
#define G_ 8             // group depth within a chunk (flat load burst)

typedef float    f4  __attribute__((ext_vector_type(4)));
typedef int      i4t __attribute__((ext_vector_type(4)));
typedef unsigned u4t __attribute__((ext_vector_type(4)));

// ===========================================================================
// Pass 1 (float4): 4 columns/thread, 16 B/lane -> 1024 B per wave load
// instruction (the width the 6.3-6.8 TB/s ceilings are measured at; R0-R4
// evidence: every 4 B/lane kernel plateaus at ~2.5-3 TB/s). Chunk of 32
// steps processed in 4 groups of 8; each group is a straight-line burst of
// 25 independent loads (8 r + 9 v + 8 d, ~25 KB in flight/wave) followed by
// fully-unrolled register compute -- no conditionals between loads (the R2
// failure mode). r/v cached (warm L3 for pass3), dones nontemporal.
// ===========================================================================
__global__ __launch_bounds__(256)
void gae_pass1_f4(const f4* __restrict__ rw, const f4* __restrict__ vv,
                  const i4t* __restrict__ dn,
                  f4* __restrict__ A, f4* __restrict__ B,
                  f4* __restrict__ Sa, f4* __restrict__ Sa2,
                  f4* __restrict__ SaP, f4* __restrict__ SP,
                  f4* __restrict__ SP2, u4t* __restrict__ mask,
                  double* __restrict__ sums, int T, int N4)
{
    if (blockIdx.x == 0 && blockIdx.y == 0 && threadIdx.x == 0) {
        sums[0] = 0.0; sums[1] = 0.0;
    }
    int q = blockIdx.x * blockDim.x + threadIdx.x;   // column-quad
    int chunk = blockIdx.y;
    if (q >= N4) return;
    int s = chunk * L_;
    int e = s + L_; if (e > T) e = T;
    int len = e - s;

    f4 a  = {0.f,0.f,0.f,0.f}, P   = {1.f,1.f,1.f,1.f};
    f4 sa = {0.f,0.f,0.f,0.f}, sa2 = {0.f,0.f,0.f,0.f};
    f4 saP= {0.f,0.f,0.f,0.f}, sP  = {0.f,0.f,0.f,0.f};
    f4 sP2= {0.f,0.f,0.f,0.f};
    u4t mm = {0u,0u,0u,0u};

    if (len == L_) {
        #pragma unroll
        for (int g = L_ / G_ - 1; g >= 0; --g) {
            int t0 = s + g * G_;
            f4 r[G_], v[G_ + 1]; i4t d[G_];
            #pragma unroll
            for (int i = 0; i < G_; ++i)
                r[i] = rw[(size_t)(t0 + i) * N4 + q];
            #pragma unroll
            for (int i = 0; i <= G_; ++i)
                v[i] = vv[(size_t)(t0 + i) * N4 + q];
            #pragma unroll
            for (int i = 0; i < G_; ++i)
                d[i] = __builtin_nontemporal_load(&dn[(size_t)(t0 + i) * N4 + q]);
            #pragma unroll
            for (int i = G_ - 1; i >= 0; --i) {
                int k = g * G_ + i;
                #pragma unroll
                for (int j = 0; j < 4; ++j) {
                    float nt = (d[i][j] == 0) ? 1.f : 0.f;
                    float delta = r[i][j] + GAMMA_ * v[i + 1][j] * nt - v[i][j];
                    float c = GL_ * nt;
                    a[j] = delta + c * a[j];
                    P[j] = c * P[j];
                    sa[j]  += a[j];
                    sa2[j] += a[j] * a[j];
                    saP[j] += a[j] * P[j];
                    sP[j]  += P[j];
                    sP2[j] += P[j] * P[j];
                    mm[j] |= (d[i][j] == 0) ? (1u << k) : 0u;
                }
            }
        }
    } else {
        f4 vnext = vv[(size_t)e * N4 + q];
        for (int t = e - 1; t >= s; --t) {
            f4  r  = rw[(size_t)t * N4 + q];
            i4t dd = dn[(size_t)t * N4 + q];
            f4  vc = vv[(size_t)t * N4 + q];
            #pragma unroll
            for (int j = 0; j < 4; ++j) {
                float nt = (dd[j] == 0) ? 1.f : 0.f;
                float delta = r[j] + GAMMA_ * vnext[j] * nt - vc[j];
                float c = GL_ * nt;
                a[j] = delta + c * a[j];
                P[j] = c * P[j];
                sa[j] += a[j]; sa2[j] += a[j]*a[j]; saP[j] += a[j]*P[j];
                sP[j] += P[j]; sP2[j] += P[j]*P[j];
                mm[j] |= (dd[j] == 0) ? (1u << (t - s)) : 0u;
            }
            vnext = vc;
        }
    }

    size_t idx = (size_t)chunk * N4 + q;
    A[idx] = a;  B[idx] = P;
    Sa[idx] = sa; Sa2[idx] = sa2; SaP[idx] = saP; SP[idx] = sP; SP2[idx] = sP2;
    mask[idx] = mm;
}

// ===========================================================================
// Pass 2 (wave-scan): one wave per column, lane l owns chunk l (C <= 64).
// ===========================================================================
__global__ __launch_bounds__(1024)
void gae_pass2_ws(const float* __restrict__ A, const float* __restrict__ B,
                  const float* __restrict__ Sa, const float* __restrict__ Sa2,
                  const float* __restrict__ SaP, const float* __restrict__ SP,
                  const float* __restrict__ SP2,
                  float* __restrict__ carry, double* __restrict__ sums,
                  int N, int C)
{
    __shared__ double psum[16], psq[16];
    int wid  = threadIdx.x >> 6;
    int lane = threadIdx.x & 63;
    int nwav = blockDim.x >> 6;
    int n = blockIdx.x * nwav + wid;

    float Ah = 0.f, Bh = 1.f;
    float sa = 0.f, sa2 = 0.f, saP = 0.f, sp = 0.f, sp2 = 0.f;
    bool act = (n < N) && (lane < C);
    size_t idx = (size_t)lane * N + n;
    if (act) {
        Ah = A[idx];  Bh = B[idx];
        sa = Sa[idx]; sa2 = Sa2[idx]; saP = SaP[idx];
        sp = SP[idx]; sp2 = SP2[idx];
    }
    #pragma unroll
    for (int d = 1; d < 64; d <<= 1) {
        float Ad = __shfl_down(Ah, d, 64);
        float Bd = __shfl_down(Bh, d, 64);
        if (lane + d < 64) { Ah = fmaf(Bh, Ad, Ah); Bh *= Bd; }
    }
    float e = __shfl_down(Ah, 1, 64);
    if (lane == 63) e = 0.f;

    double lsum = 0.0, lsq = 0.0;
    if (act) {
        carry[idx] = e;
        lsum = (double)(sa + sp * e);
        lsq  = (double)(sa2 + 2.0f * e * saP + (e * e) * sp2);
    }
    for (int off = 32; off > 0; off >>= 1) {
        lsum += __shfl_down(lsum, off, 64);
        lsq  += __shfl_down(lsq, off, 64);
    }
    if (lane == 0) { psum[wid] = lsum; psq[wid] = lsq; }
    __syncthreads();
    if (threadIdx.x == 0) {
        double s = 0.0, s2 = 0.0;
        for (int w = 0; w < nwav; ++w) { s += psum[w]; s2 += psq[w]; }
        atomicAdd(&sums[0], s);
        atomicAdd(&sums[1], s2);
    }
}

__global__ __launch_bounds__(64)
void gae_pass2_seq(const float* __restrict__ A, const float* __restrict__ B,
                   const float* __restrict__ Sa, const float* __restrict__ Sa2,
                   const float* __restrict__ SaP, const float* __restrict__ SP,
                   const float* __restrict__ SP2,
                   float* __restrict__ carry, double* __restrict__ sums,
                   int N, int C)
{
    int n = blockIdx.x * blockDim.x + threadIdx.x;
    double lsum = 0.0, lsq = 0.0;
    if (n < N) {
        float g = 0.f;
        for (int i = C - 1; i >= 0; --i) {
            int idx = i * N + n;
            carry[idx] = g;
            float e = g;
            lsum += (double)(Sa[idx] + SP[idx] * e);
            lsq  += (double)(Sa2[idx] + 2.0f * e * SaP[idx] + (e * e) * SP2[idx]);
            g = A[idx] + B[idx] * g;
        }
    }
    for (int off = 32; off > 0; off >>= 1) {
        lsum += __shfl_down(lsum, off, 64);
        lsq  += __shfl_down(lsq, off, 64);
    }
    if ((threadIdx.x & 63) == 0) {
        atomicAdd(&sums[0], lsum);
        atomicAdd(&sums[1], lsq);
    }
}

// ===========================================================================
// Pass 3 (float4): rescan with true carry, normalize, emit. Same group-of-8
// flat-burst structure; r/v loads cached (L3-warm from pass1); outputs are
// write-once -> nontemporal dwordx4 stores.
// ===========================================================================
__global__ __launch_bounds__(256)
void gae_pass3_f4(const f4* __restrict__ rw, const f4* __restrict__ vv,
                  const u4t* __restrict__ mask, const f4* __restrict__ carry,
                  const double* __restrict__ sums,
                  f4* __restrict__ out_adv, f4* __restrict__ out_ret,
                  int T, int N4, double Minv, double Mm1inv)
{
    int q = blockIdx.x * blockDim.x + threadIdx.x;
    int chunk = blockIdx.y;
    if (q >= N4) return;
    int s = chunk * L_;
    int e = s + L_; if (e > T) e = T;
    int len = e - s;

    double S = sums[0], S2 = sums[1];
    float mean = (float)(S * Minv);
    double vard = (S2 - S * S * Minv) * Mm1inv;
    float inv = (float)(1.0 / (sqrt(vard) + 1e-8));

    size_t idx = (size_t)chunk * N4 + q;
    f4 a = carry[idx];
    u4t mm = mask[idx];

    if (len == L_) {
        #pragma unroll
        for (int g = L_ / G_ - 1; g >= 0; --g) {
            int t0 = s + g * G_;
            f4 r[G_], v[G_ + 1];
            #pragma unroll
            for (int i = 0; i < G_; ++i)
                r[i] = rw[(size_t)(t0 + i) * N4 + q];
            #pragma unroll
            for (int i = 0; i <= G_; ++i)
                v[i] = vv[(size_t)(t0 + i) * N4 + q];
            #pragma unroll
            for (int i = G_ - 1; i >= 0; --i) {
                int k = g * G_ + i;
                f4 oa, orr;
                #pragma unroll
                for (int j = 0; j < 4; ++j) {
                    float nt = (mm[j] & (1u << k)) ? 1.f : 0.f;
                    float delta = r[i][j] + GAMMA_ * v[i + 1][j] * nt - v[i][j];
                    a[j] = delta + GL_ * nt * a[j];
                    oa[j]  = (a[j] - mean) * inv;
                    orr[j] = a[j] + v[i][j];
                }
                size_t off = (size_t)(t0 + i) * N4 + q;
                __builtin_nontemporal_store(oa,  &out_adv[off]);
                __builtin_nontemporal_store(orr, &out_ret[off]);
            }
        }
    } else {
        f4 vnext = vv[(size_t)e * N4 + q];
        for (int t = e - 1; t >= s; --t) {
            size_t off = (size_t)t * N4 + q;
            f4 r  = rw[off];
            f4 vc = vv[off];
            f4 oa, orr;
            #pragma unroll
            for (int j = 0; j < 4; ++j) {
                float nt = (mm[j] & (1u << (t - s))) ? 1.f : 0.f;
                float delta = r[j] + GAMMA_ * vnext[j] * nt - vc[j];
                a[j] = delta + GL_ * nt * a[j];
                oa[j]  = (a[j] - mean) * inv;
                orr[j] = a[j] + vc[j];
            }
            __builtin_nontemporal_store(oa,  &out_adv[off]);
            __builtin_nontemporal_store(orr, &out_ret[off]);
            vnext = vc;
        }
    }
}

// ===========================================================================
// Scalar fallbacks (N % 4 != 0) -- round-3 verified versions.
// ===========================================================================
__global__ __launch_bounds__(256)
void gae_pass1_s(const float* __restrict__ rw, const float* __restrict__ vv,
                 const int* __restrict__ dn,
                 float* __restrict__ A, float* __restrict__ B,
                 float* __restrict__ Sa, float* __restrict__ Sa2,
                 float* __restrict__ SaP, float* __restrict__ SP,
                 float* __restrict__ SP2, unsigned* __restrict__ mask,
                 double* __restrict__ sums, int T, int N)
{
    if (blockIdx.x == 0 && blockIdx.y == 0 && threadIdx.x == 0) {
        sums[0] = 0.0; sums[1] = 0.0;
    }
    int n = blockIdx.x * blockDim.x + threadIdx.x;
    int chunk = blockIdx.y;
    if (n >= N) return;
    int s = chunk * L_;
    int e = s + L_; if (e > T) e = T;

    float a = 0.f, P = 1.f;
    float sa = 0.f, sa2 = 0.f, saP = 0.f, sP = 0.f, sP2 = 0.f;
    unsigned mm = 0u;
    float vnext = vv[(size_t)e * N + n];
    for (int t = e - 1; t >= s; --t) {
        size_t off = (size_t)t * N + n;
        float r = rw[off];
        int   dd = dn[off];
        float vc = vv[off];
        float nt = (dd == 0) ? 1.0f : 0.0f;
        float delta = r + GAMMA_ * vnext * nt - vc;
        float c = GL_ * nt;
        a = delta + c * a;
        P = c * P;
        sa += a; sa2 += a * a; saP += a * P; sP += P; sP2 += P * P;
        mm |= (dd == 0) ? (1u << (t - s)) : 0u;
        vnext = vc;
    }
    size_t idx = (size_t)chunk * N + n;
    A[idx] = a;  B[idx] = P;
    Sa[idx] = sa; Sa2[idx] = sa2; SaP[idx] = saP; SP[idx] = sP; SP2[idx] = sP2;
    mask[idx] = mm;
}

__global__ __launch_bounds__(256)
void gae_pass3_s(const float* __restrict__ rw, const float* __restrict__ vv,
                 const unsigned* __restrict__ mask, const float* __restrict__ carry,
                 const double* __restrict__ sums,
                 float* __restrict__ out_adv, float* __restrict__ out_ret,
                 int T, int N, double Minv, double Mm1inv)
{
    int n = blockIdx.x * blockDim.x + threadIdx.x;
    int chunk = blockIdx.y;
    if (n >= N) return;
    int s = chunk * L_;
    int e = s + L_; if (e > T) e = T;

    double S = sums[0], S2 = sums[1];
    float mean = (float)(S * Minv);
    double vard = (S2 - S * S * Minv) * Mm1inv;
    float inv = (float)(1.0 / (sqrt(vard) + 1e-8));

    size_t idx = (size_t)chunk * N + n;
    float a = carry[idx];
    unsigned mm = mask[idx];
    float vnext = vv[(size_t)e * N + n];
    for (int t = e - 1; t >= s; --t) {
        size_t off = (size_t)t * N + n;
        float r = rw[off];
        float vc = vv[off];
        float nt = (mm & (1u << (t - s))) ? 1.0f : 0.0f;
        float delta = r + GAMMA_ * vnext * nt - vc;
        a = delta + GL_ * nt * a;
        __builtin_nontemporal_store((a - mean) * inv, &out_adv[off]);
        __builtin_nontemporal_store(a + vc,          &out_ret[off]);
        vnext = vc;
    }
}

extern "C" void kernel_launch(void* const* d_in, const int* in_sizes, int n_in,
                              void* d_out, int out_size, void* d_ws, size_t ws_size,
                              hipStream_t stream)
{
    const float* rw = (const float*)d_in[0];
    const float* vv = (const float*)d_in[1];
    const int*   dn = (const int*)d_in[2];

    long long TN = in_sizes[0];          // T*N
    long long VN = in_sizes[1];          // (T+1)*N
    int N = (int)(VN - TN);
    int T = (int)(TN / N);
    int C = (T + L_ - 1) / L_;           // 64 for T=2048
    double M = (double)TN;
    double Minv = 1.0 / M, Mm1inv = 1.0 / (M - 1.0);

    float* out_adv = (float*)d_out;
    float* out_ret = (float*)d_out + TN;

    // Workspace: [2 doubles][mask: C*N u32][8 float arrays of C*N]
    char* ws = (char*)d_ws;
    double* sums = (double*)ws;
    size_t cn = (size_t)C * N;
    unsigned* mask = (unsigned*)(ws + 16);
    float* f   = (float*)(ws + 16 + cn * 4);
    float* A   = f;
    float* B   = f + cn;
    float* Sa  = f + 2 * cn;
    float* Sa2 = f + 3 * cn;
    float* SaP = f + 4 * cn;
    float* SP  = f + 5 * cn;
    float* SP2 = f + 6 * cn;
    float* cry = f + 7 * cn;

    dim3 blk(256);
    if (N % 4 == 0) {
        int N4 = N / 4;
        dim3 g1((N4 + 255) / 256, C);
        gae_pass1_f4<<<g1, blk, 0, stream>>>(
            (const f4*)rw, (const f4*)vv, (const i4t*)dn,
            (f4*)A, (f4*)B, (f4*)Sa, (f4*)Sa2, (f4*)SaP,
            (f4*)SP, (f4*)SP2, (u4t*)mask, sums, T, N4);
    } else {
        dim3 g1((N + 255) / 256, C);
        gae_pass1_s<<<g1, blk, 0, stream>>>(
            rw, vv, dn, A, B, Sa, Sa2, SaP, SP, SP2, mask, sums, T, N);
    }

    if (C <= 64) {
        int wpb = 16;
        gae_pass2_ws<<<dim3((N + wpb - 1) / wpb), dim3(wpb * 64), 0, stream>>>(
            A, B, Sa, Sa2, SaP, SP, SP2, cry, sums, N, C);
    } else {
        gae_pass2_seq<<<dim3((N + 63) / 64), dim3(64), 0, stream>>>(
            A, B, Sa, Sa2, SaP, SP, SP2, cry, sums, N, C);
    }

    if (N % 4 == 0) {
        int N4 = N / 4;
        dim3 g1((N4 + 255) / 256, C);
        gae_pass3_f4<<<g1, blk, 0, stream>>>(
            (const f4*)rw, (const f4*)vv, (const u4t*)mask, (const f4*)cry,
            sums, (f4*)out_adv, (f4*)out_ret, T, N4, Minv, Mm1inv);
    } else {
        dim3 g1((N + 255) / 256, C);
        gae_pass3_s<<<g1, blk, 0, stream>>>(
            rw, vv, mask, cry, sums, out_adv, out_ret, T, N, Minv, Mm1inv);
    }
}